// Round 1
// baseline (951.596 us; speedup 1.0000x reference)
//
#include <hip/hip_runtime.h>
#include <hip/hip_bf16.h>

typedef unsigned short u16;
typedef __attribute__((ext_vector_type(8))) short bh8;   // 8 x bf16 (4 VGPRs)
typedef __attribute__((ext_vector_type(4))) float fx4;   // MFMA accumulator

__device__ __forceinline__ u16 f2bf(float f) {
  union { float f; unsigned u; } v; v.f = f;
  unsigned r = v.u + 0x7FFFu + ((v.u >> 16) & 1u);  // RNE
  return (u16)(r >> 16);
}

__device__ __forceinline__ void gload_lds16(const void* g, void* l) {
  __builtin_amdgcn_global_load_lds(
      (const __attribute__((address_space(1))) void*)g,
      (__attribute__((address_space(3))) void*)l, 16, 0, 0);
}

// ---------------- weight transpose + f32->bf16 : W[K][N] -> Wt[N][K] ----------------
__global__ __launch_bounds__(256) void transp_cvt(
    const float* __restrict__ W, u16* __restrict__ Wt, int K, int N) {
  __shared__ float tile[32][33];
  const int k0 = blockIdx.x * 32, n0 = blockIdx.y * 32;
  const int tx = threadIdx.x & 31, ty = threadIdx.x >> 5;  // ty 0..7
#pragma unroll
  for (int i = 0; i < 4; ++i)
    tile[ty + i * 8][tx] = W[(size_t)(k0 + ty + i * 8) * N + n0 + tx];
  __syncthreads();
#pragma unroll
  for (int i = 0; i < 4; ++i)
    Wt[(size_t)(n0 + ty + i * 8) * K + k0 + tx] = f2bf(tile[tx][ty + i * 8]);
}

// ---------------- block reduce ----------------
__device__ __forceinline__ float blockSum(float v, float* sh) {
#pragma unroll
  for (int m = 32; m; m >>= 1) v += __shfl_xor(v, m);
  if ((threadIdx.x & 63) == 0) sh[threadIdx.x >> 6] = v;
  __syncthreads();
  return sh[0] + sh[1] + sh[2] + sh[3];
}

// ---------------- LN1: x[b, j] -> hw windowed/rolled bf16 [16][2048][768] ----------------
__global__ __launch_bounds__(256) void ln1_k(
    const float* __restrict__ x, const float* __restrict__ w,
    const float* __restrict__ b, u16* __restrict__ hw) {
  __shared__ float sh1[4], sh2[4];
  const int row = blockIdx.x;            // 0..32767 (b*2048 + i, rolled coords)
  const int bI = row >> 11, i = row & 2047;
  const int j = (i + 64) & 2047;         // source (unrolled) index
  const int tid = threadIdx.x;
  u16* dst = hw + (size_t)row * 768;
  if (j >= 2000) {                       // padded region -> zeros
    dst[tid] = 0; dst[tid + 256] = 0; dst[tid + 512] = 0;
    return;
  }
  const float* xr = x + ((size_t)bI * 2000 + j) * 768;
  float v0 = xr[tid], v1 = xr[tid + 256], v2 = xr[tid + 512];
  float mean = blockSum(v0 + v1 + v2, sh1) * (1.0f / 768.0f);
  float d0 = v0 - mean, d1 = v1 - mean, d2 = v2 - mean;
  float var = blockSum(d0 * d0 + d1 * d1 + d2 * d2, sh2) * (1.0f / 768.0f);
  float rs = rsqrtf(var + 1e-5f);
  dst[tid]       = f2bf(d0 * rs * w[tid]       + b[tid]);
  dst[tid + 256] = f2bf(d1 * rs * w[tid + 256] + b[tid + 256]);
  dst[tid + 512] = f2bf(d2 * rs * w[tid + 512] + b[tid + 512]);
}

// ---------------- LN2: x2 (f32, 32000 rows) -> h2 bf16 ----------------
__global__ __launch_bounds__(256) void ln2_k(
    const float* __restrict__ src, const float* __restrict__ w,
    const float* __restrict__ b, u16* __restrict__ dsth) {
  __shared__ float sh1[4], sh2[4];
  const int row = blockIdx.x;
  const int tid = threadIdx.x;
  const float* xr = src + (size_t)row * 768;
  u16* dst = dsth + (size_t)row * 768;
  float v0 = xr[tid], v1 = xr[tid + 256], v2 = xr[tid + 512];
  float mean = blockSum(v0 + v1 + v2, sh1) * (1.0f / 768.0f);
  float d0 = v0 - mean, d1 = v1 - mean, d2 = v2 - mean;
  float var = blockSum(d0 * d0 + d1 * d1 + d2 * d2, sh2) * (1.0f / 768.0f);
  float rs = rsqrtf(var + 1e-5f);
  dst[tid]       = f2bf(d0 * rs * w[tid]       + b[tid]);
  dst[tid + 256] = f2bf(d1 * rs * w[tid + 256] + b[tid + 256]);
  dst[tid + 512] = f2bf(d2 * rs * w[tid + 512] + b[tid + 512]);
}

// ---------------- GEMM: C = A[M,K] * Bt[N,K]^T, m97-style 128x128 tile ----------------
enum { EQKV = 0, EPROJ = 1, EFC1 = 2, EFC2 = 3 };

template <int EPI>
__global__ __launch_bounds__(256, 2) void gemm_k(
    const u16* __restrict__ A, const u16* __restrict__ Bt,
    const float* __restrict__ bias, const float* __restrict__ lsv,
    const float* __restrict__ resid, float* __restrict__ outf,
    u16* __restrict__ outh, int M, int N, int K) {
  __shared__ u16 As[128][32];
  __shared__ u16 Bs[128][32];
  const int tid = threadIdx.x;
  const int lane = tid & 63, wid = tid >> 6;
  const int m0 = blockIdx.x * 128, n0 = blockIdx.y * 128;
  (void)M;

  fx4 acc[4][4];
#pragma unroll
  for (int i = 0; i < 4; ++i)
#pragma unroll
    for (int j = 0; j < 4; ++j) acc[i][j] = fx4{0.f, 0.f, 0.f, 0.f};

  // staging: each wave stages a 32-row quarter of each tile, 2x global_load_lds(16B)
  const int srow = wid * 32 + (lane >> 2);
  const int scol = (lane & 3) * 8;
  const u16* aSrc = A + (size_t)(m0 + srow) * K + scol;
  const u16* bSrc = Bt + (size_t)(n0 + srow) * K + scol;
  u16* aDst = &As[wid * 32][0];
  u16* bDst = &Bs[wid * 32][0];
  const int wr = wid >> 1, wc = wid & 1;       // 2x2 waves, 64x64 each
  const int rsel = lane & 15, ksel = (lane >> 4) * 8;

  for (int k0 = 0; k0 < K; k0 += 32) {
    gload_lds16(aSrc + k0, aDst);
    gload_lds16(aSrc + k0 + (size_t)16 * K, aDst + 16 * 32);
    gload_lds16(bSrc + k0, bDst);
    gload_lds16(bSrc + k0 + (size_t)16 * K, bDst + 16 * 32);
    __syncthreads();

    bh8 af[4], bf[4];
#pragma unroll
    for (int mi = 0; mi < 4; ++mi)
      af[mi] = *(const bh8*)&As[wr * 64 + mi * 16 + rsel][ksel];
#pragma unroll
    for (int ni = 0; ni < 4; ++ni)
      bf[ni] = *(const bh8*)&Bs[wc * 64 + ni * 16 + rsel][ksel];
#pragma unroll
    for (int mi = 0; mi < 4; ++mi)
#pragma unroll
      for (int ni = 0; ni < 4; ++ni)
        acc[mi][ni] = __builtin_amdgcn_mfma_f32_16x16x32_bf16(
            af[mi], bf[ni], acc[mi][ni], 0, 0, 0);
    __syncthreads();
  }

  // epilogue; C/D layout: col = lane&15, row = (lane>>4)*4 + j   [m89-verified]
  const int cc = lane & 15;
  const int rbase = (lane >> 4) * 4;
#pragma unroll
  for (int mi = 0; mi < 4; ++mi) {
#pragma unroll
    for (int ni = 0; ni < 4; ++ni) {
      const int gc = n0 + wc * 64 + ni * 16 + cc;
      const float bv = bias[gc];
#pragma unroll
      for (int j = 0; j < 4; ++j) {
        const int gr = m0 + wr * 64 + mi * 16 + rbase + j;
        const float v = acc[mi][ni][j] + bv;
        if (EPI == EQKV) {
          outh[(size_t)gr * N + gc] = f2bf(v);
        } else if (EPI == EFC1) {
          const float t = 0.5f * v * (1.0f + erff(v * 0.70710678118654752f));
          outh[(size_t)gr * N + gc] = f2bf(t);
        } else if (EPI == EFC2) {
          const size_t o = (size_t)gr * 768 + gc;
          outf[o] += v * lsv[gc];
        } else {  // EPROJ: unroll(+64), crop, x2 = x + a*ls1
          const int bI = gr >> 11, ip = gr & 2047;
          const int jj = (ip + 64) & 2047;
          if (jj < 2000) {
            const size_t o = ((size_t)bI * 2000 + jj) * 768 + gc;
            outf[o] = resid[o] + v * lsv[gc];
          }
        }
      }
    }
  }
}

// ---------------- window attention: one block per (window, head) ----------------
struct AttnLds {
  union {
    struct { u16 Qs[128][72]; u16 Ks[128][72]; } qk;  // 36864 B
    u16 Ps[128][136];                                  // 34816 B
  } u;
  u16 Vt[64][136];   // V^T: [d][kk], 17408 B
  float biasv[256];  // rel_bias column for this head
};

__global__ __launch_bounds__(256, 2) void attn_k(
    const u16* __restrict__ qkv, const float* __restrict__ rel_bias,
    u16* __restrict__ aout) {
  __shared__ AttnLds L;
  const int blk = blockIdx.x;
  const int w = blk / 12, h = blk - w * 12;
  const int wi = w & 15;  // window index within batch
  const int tid = threadIdx.x;
  const int lane = tid & 63, wid = tid >> 6;

  if (tid < 255) L.biasv[tid] = rel_bias[tid * 12 + h];

  const size_t rowbase = (size_t)w * 128;
#pragma unroll
  for (int i = 0; i < 4; ++i) {
    const int idx = tid + i * 256;          // 0..1023
    const int r = idx >> 3, seg = idx & 7;  // 128 rows x 8 segs of 8
    const u16* src = qkv + (rowbase + r) * 2304 + h * 64 + seg * 8;
    *(bh8*)&L.u.qk.Qs[r][seg * 8] = *(const bh8*)(src);
    *(bh8*)&L.u.qk.Ks[r][seg * 8] = *(const bh8*)(src + 768);
    bh8 vv = *(const bh8*)(src + 1536);
#pragma unroll
    for (int e = 0; e < 8; ++e) L.Vt[seg * 8 + e][r] = ((const u16*)&vv)[e];
  }
  __syncthreads();

  // QK^T: each wave owns 32 q-rows x all 128 k-cols
  const int R0 = wid * 32;
  const int rsel = lane & 15, kgrp = lane >> 4;
  fx4 s[2][8];
#pragma unroll
  for (int mi = 0; mi < 2; ++mi)
#pragma unroll
    for (int ni = 0; ni < 8; ++ni) s[mi][ni] = fx4{0.f, 0.f, 0.f, 0.f};

#pragma unroll
  for (int ks = 0; ks < 2; ++ks) {
    bh8 aq[2], bk[8];
#pragma unroll
    for (int mi = 0; mi < 2; ++mi)
      aq[mi] = *(const bh8*)&L.u.qk.Qs[R0 + mi * 16 + rsel][ks * 32 + kgrp * 8];
#pragma unroll
    for (int ni = 0; ni < 8; ++ni)
      bk[ni] = *(const bh8*)&L.u.qk.Ks[ni * 16 + rsel][ks * 32 + kgrp * 8];
#pragma unroll
    for (int mi = 0; mi < 2; ++mi)
#pragma unroll
      for (int ni = 0; ni < 8; ++ni)
        s[mi][ni] = __builtin_amdgcn_mfma_f32_16x16x32_bf16(aq[mi], bk[ni], s[mi][ni], 0, 0, 0);
  }

  // scale + rel-bias + mask + row softmax (rows live in a 16-lane group)
#pragma unroll
  for (int mi = 0; mi < 2; ++mi) {
#pragma unroll
    for (int j = 0; j < 4; ++j) {
      const int r = R0 + mi * 16 + kgrp * 4 + j;
      float vals[8];
      float mx = -1e30f;
#pragma unroll
      for (int ni = 0; ni < 8; ++ni) {
        const int c = ni * 16 + rsel;
        const int ic = wi * 128 + c;
        const bool valid = ((ic + 64) & 2047) < 2000;
        const float v = valid ? (s[mi][ni][j] * 0.125f + L.biasv[c - r + 127]) : -1e30f;
        vals[ni] = v;
        mx = fmaxf(mx, v);
      }
#pragma unroll
      for (int mm = 8; mm; mm >>= 1) mx = fmaxf(mx, __shfl_xor(mx, mm));
      float sum = 0.f;
#pragma unroll
      for (int ni = 0; ni < 8; ++ni) { float p = __expf(vals[ni] - mx); vals[ni] = p; sum += p; }
#pragma unroll
      for (int mm = 8; mm; mm >>= 1) sum += __shfl_xor(sum, mm);
      const float inv = 1.0f / sum;
#pragma unroll
      for (int ni = 0; ni < 8; ++ni) s[mi][ni][j] = vals[ni] * inv;
    }
  }
  __syncthreads();  // all QK^T LDS reads done before P overwrites Q/K (union)

#pragma unroll
  for (int mi = 0; mi < 2; ++mi)
#pragma unroll
    for (int ni = 0; ni < 8; ++ni)
#pragma unroll
      for (int j = 0; j < 4; ++j)
        L.u.Ps[R0 + mi * 16 + kgrp * 4 + j][ni * 16 + rsel] = f2bf(s[mi][ni][j]);
  __syncthreads();

  // PV: out 32x64 per wave
  fx4 o[2][4];
#pragma unroll
  for (int mi = 0; mi < 2; ++mi)
#pragma unroll
    for (int ni = 0; ni < 4; ++ni) o[mi][ni] = fx4{0.f, 0.f, 0.f, 0.f};
#pragma unroll
  for (int ks = 0; ks < 4; ++ks) {
    bh8 ap[2], bv[4];
#pragma unroll
    for (int mi = 0; mi < 2; ++mi)
      ap[mi] = *(const bh8*)&L.u.Ps[R0 + mi * 16 + rsel][ks * 32 + kgrp * 8];
#pragma unroll
    for (int ni = 0; ni < 4; ++ni)
      bv[ni] = *(const bh8*)&L.Vt[ni * 16 + rsel][ks * 32 + kgrp * 8];
#pragma unroll
    for (int mi = 0; mi < 2; ++mi)
#pragma unroll
      for (int ni = 0; ni < 4; ++ni)
        o[mi][ni] = __builtin_amdgcn_mfma_f32_16x16x32_bf16(ap[mi], bv[ni], o[mi][ni], 0, 0, 0);
  }

#pragma unroll
  for (int mi = 0; mi < 2; ++mi)
#pragma unroll
    for (int ni = 0; ni < 4; ++ni)
#pragma unroll
      for (int j = 0; j < 4; ++j)
        aout[(rowbase + R0 + mi * 16 + kgrp * 4 + j) * 768 + h * 64 + ni * 16 + rsel] =
            f2bf(o[mi][ni][j]);
}

// ---------------- host ----------------
extern "C" void kernel_launch(void* const* d_in, const int* in_sizes, int n_in,
                              void* d_out, int out_size, void* d_ws, size_t ws_size,
                              hipStream_t stream) {
  (void)in_sizes; (void)n_in; (void)out_size; (void)ws_size;
  const float* x        = (const float*)d_in[0];
  const float* n1w      = (const float*)d_in[1];
  const float* n1b      = (const float*)d_in[2];
  const float* qkv_w    = (const float*)d_in[3];
  const float* qkv_b    = (const float*)d_in[4];
  const float* proj_w   = (const float*)d_in[5];
  const float* proj_b   = (const float*)d_in[6];
  const float* rel_bias = (const float*)d_in[7];
  const float* ls1      = (const float*)d_in[8];
  const float* n2w      = (const float*)d_in[9];
  const float* n2b      = (const float*)d_in[10];
  const float* fc1_w    = (const float*)d_in[11];
  const float* fc1_b    = (const float*)d_in[12];
  const float* fc2_w    = (const float*)d_in[13];
  const float* fc2_b    = (const float*)d_in[14];
  const float* ls2      = (const float*)d_in[15];
  float* out = (float*)d_out;

  char* ws = (char*)d_ws;
  u16* WtQ  = (u16*)(ws);                                   //  768x2304^T : 3,538,944 B
  u16* WtP  = (u16*)(ws + 3538944);                         //  768x768^T  : 1,179,648 B
  u16* WtF1 = (u16*)(ws + 4718592);                         //  768x3072^T : 4,718,592 B
  u16* WtF2 = (u16*)(ws + 9437184);                         // 3072x768^T  : 4,718,592 B
  u16* bufB = (u16*)(ws + 14155776);                        // hw/attn/h2  : 50,331,648 B
  u16* bufA = (u16*)(ws + 14155776 + 50331648);             // qkv/g-half  : 150,994,944 B

  dim3 t256(256);
  transp_cvt<<<dim3(24, 72), t256, 0, stream>>>(qkv_w, WtQ, 768, 2304);
  transp_cvt<<<dim3(24, 24), t256, 0, stream>>>(proj_w, WtP, 768, 768);
  transp_cvt<<<dim3(24, 96), t256, 0, stream>>>(fc1_w, WtF1, 768, 3072);
  transp_cvt<<<dim3(96, 24), t256, 0, stream>>>(fc2_w, WtF2, 3072, 768);

  ln1_k<<<32768, t256, 0, stream>>>(x, n1w, n1b, bufB);
  gemm_k<EQKV><<<dim3(256, 18), t256, 0, stream>>>(
      bufB, WtQ, qkv_b, nullptr, nullptr, nullptr, bufA, 32768, 2304, 768);
  attn_k<<<3072, t256, 0, stream>>>(bufA, rel_bias, bufB);
  gemm_k<EPROJ><<<dim3(256, 6), t256, 0, stream>>>(
      bufB, WtP, proj_b, ls1, x, out, nullptr, 32768, 768, 768);
  ln2_k<<<32000, t256, 0, stream>>>(out, n2w, n2b, bufB);
  for (int half = 0; half < 2; ++half) {
    const u16* h2h = bufB + (size_t)half * 16000 * 768;
    float* outh = out + (size_t)half * 16000 * 768;
    gemm_k<EFC1><<<dim3(125, 24), t256, 0, stream>>>(
        h2h, WtF1, fc1_b, nullptr, nullptr, nullptr, bufA, 16000, 3072, 768);
    gemm_k<EFC2><<<dim3(125, 6), t256, 0, stream>>>(
        bufA, WtF2, fc2_b, ls2, nullptr, outh, nullptr, 16000, 768, 3072);
  }
}